// Round 1
// baseline (2149.622 us; speedup 1.0000x reference)
//
#include <hip/hip_runtime.h>
#include <cstdint>
#include <cstddef>

// GraphSAGE 3-layer, mean aggregation, fp32.
// Plan: build CSR (deg -> prefix scan -> fill), then per layer:
//   agg[i,:] = inv_deg[i] * sum_{j in N(i)} h[j,:]   (atomic-free, block per node)
//   out = relu([agg | h] @ [Wl; Wr] + bl)            (fused fp32 LDS-tiled GEMM)
// Workspace needed: ~106 MB (csr 3.2MB + aggs 51MB + h1 51MB + small arrays).
// h0 is stored in d_out and overwritten by the final layer (which never reads it).

static inline size_t align_up(size_t x, size_t a) { return (x + a - 1) / a * a; }

__global__ void deg_kernel(const int* __restrict__ dst, int* __restrict__ deg, int E) {
    int i = blockIdx.x * blockDim.x + threadIdx.x;
    if (i < E) atomicAdd(&deg[dst[i]], 1);
}

// Single block, 1024 threads: chunked exclusive scan of deg -> rowptr, cursor, inv_deg.
__global__ void scan_kernel(const int* __restrict__ deg, int* __restrict__ rowptr,
                            int* __restrict__ cursor, float* __restrict__ inv_deg, int n) {
    __shared__ int sums[1024];
    int tid = threadIdx.x;
    int chunk = (n + 1023) >> 10;
    int start = tid * chunk;
    int end = min(start + chunk, n);
    if (start > n) { start = n; end = n; }
    int s = 0;
    for (int i = start; i < end; ++i) s += deg[i];
    sums[tid] = s;
    __syncthreads();
    for (int off = 1; off < 1024; off <<= 1) {
        int v = (tid >= off) ? sums[tid - off] : 0;
        __syncthreads();
        sums[tid] += v;
        __syncthreads();
    }
    int run = sums[tid] - s;  // exclusive prefix for this chunk
    for (int i = start; i < end; ++i) {
        int d = deg[i];
        rowptr[i] = run;
        cursor[i] = run;
        inv_deg[i] = d > 0 ? 1.0f / (float)d : 0.0f;
        run += d;
    }
    if (tid == 1023) rowptr[n] = run;
}

__global__ void fill_kernel(const int* __restrict__ src, const int* __restrict__ dst,
                            int* __restrict__ cursor, int* __restrict__ csr, int E) {
    int i = blockIdx.x * blockDim.x + threadIdx.x;
    if (i < E) {
        int p = atomicAdd(&cursor[dst[i]], 1);
        csr[p] = src[i];
    }
}

// One block per node; thread t owns feature t. 4-way unrolled gather-sum.
template<int C>
__global__ void agg_kernel(const float* __restrict__ h, const int* __restrict__ rowptr,
                           const int* __restrict__ csr, const float* __restrict__ inv_deg,
                           float* __restrict__ aggs) {
    int node = blockIdx.x;
    int t = threadIdx.x;
    int b = rowptr[node], e = rowptr[node + 1];
    float a0 = 0.f, a1 = 0.f, a2 = 0.f, a3 = 0.f;
    int k = b;
    for (; k + 3 < e; k += 4) {
        int s0 = csr[k], s1 = csr[k + 1], s2 = csr[k + 2], s3 = csr[k + 3];
        a0 += h[(size_t)s0 * C + t];
        a1 += h[(size_t)s1 * C + t];
        a2 += h[(size_t)s2 * C + t];
        a3 += h[(size_t)s3 * C + t];
    }
    for (; k < e; ++k) a0 += h[(size_t)csr[k] * C + t];
    aggs[(size_t)node * C + t] = ((a0 + a1) + (a2 + a3)) * inv_deg[node];
}

// out[i,c] = relu( sum_k A1[i,k]*W1[k,c] + sum_k A2[i,k]*W2[k,c] + bias[c] )
// BM=64 rows x BN=256 cols per block, BK=32. 256 threads: wave w handles rows
// w*16..w*16+15; lane owns 4 consecutive cols. A-reads broadcast, W-reads
// lane-consecutive b128 (conflict-free).
template<int K1>
__global__ void gemm_fused(const float* __restrict__ A1, const float* __restrict__ A2,
                           const float* __restrict__ W1, const float* __restrict__ W2,
                           const float* __restrict__ bias, float* __restrict__ out, int n) {
    constexpr int BM = 64, BK = 32;
    __shared__ float As[BM * BK];    // 8 KB
    __shared__ float Ws[BK * 256];   // 32 KB
    int tid = threadIdx.x;
    int lane = tid & 63;
    int wave = tid >> 6;
    int row0 = blockIdx.x * BM;

    float acc[16][4];
    #pragma unroll
    for (int i = 0; i < 16; ++i)
        #pragma unroll
        for (int j = 0; j < 4; ++j) acc[i][j] = 0.f;

    constexpr int NT = (2 * K1) / BK;
    #pragma unroll 1
    for (int kt = 0; kt < NT; ++kt) {
        int kg = kt * BK;
        const float* A = (kg < K1) ? A1 : A2;
        const float* W = (kg < K1) ? W1 : W2;
        int kofs = (kg < K1) ? kg : (kg - K1);
        // stage A tile: 64x32 floats, 2 float4 per thread
        {
            int r = tid >> 3;               // 0..31
            int k4 = (tid & 7) * 4;
            #pragma unroll
            for (int p = 0; p < 2; ++p) {
                int row = r + p * 32;
                float4 v = make_float4(0.f, 0.f, 0.f, 0.f);
                int gr = row0 + row;
                if (gr < n) v = *(const float4*)(A + (size_t)gr * K1 + kofs + k4);
                *(float4*)(As + row * BK + k4) = v;
            }
        }
        // stage W tile: 32x256 floats, 8 float4 per thread (per wave: one k-row, contiguous)
        {
            int c4 = (tid & 63) * 4;
            int kk = tid >> 6;              // 0..3
            #pragma unroll
            for (int p = 0; p < 8; ++p) {
                int k = kk + p * 4;
                *(float4*)(Ws + k * 256 + c4) = *(const float4*)(W + (size_t)(kofs + k) * 256 + c4);
            }
        }
        __syncthreads();
        const float4* As4 = (const float4*)As;
        const float4* Ws4 = (const float4*)Ws;
        #pragma unroll
        for (int kb = 0; kb < 8; ++kb) {
            float4 w0 = Ws4[(kb * 4 + 0) * 64 + lane];
            float4 w1 = Ws4[(kb * 4 + 1) * 64 + lane];
            float4 w2 = Ws4[(kb * 4 + 2) * 64 + lane];
            float4 w3 = Ws4[(kb * 4 + 3) * 64 + lane];
            #pragma unroll
            for (int i = 0; i < 16; ++i) {
                float4 a = As4[(wave * 16 + i) * 8 + kb];
                acc[i][0] += a.x * w0.x; acc[i][1] += a.x * w0.y; acc[i][2] += a.x * w0.z; acc[i][3] += a.x * w0.w;
                acc[i][0] += a.y * w1.x; acc[i][1] += a.y * w1.y; acc[i][2] += a.y * w1.z; acc[i][3] += a.y * w1.w;
                acc[i][0] += a.z * w2.x; acc[i][1] += a.z * w2.y; acc[i][2] += a.z * w2.z; acc[i][3] += a.z * w2.w;
                acc[i][0] += a.w * w3.x; acc[i][1] += a.w * w3.y; acc[i][2] += a.w * w3.z; acc[i][3] += a.w * w3.w;
            }
        }
        __syncthreads();
    }

    float4 b4 = *(const float4*)(bias + lane * 4);
    #pragma unroll
    for (int i = 0; i < 16; ++i) {
        int gr = row0 + wave * 16 + i;
        if (gr < n) {
            float4 v;
            v.x = fmaxf(acc[i][0] + b4.x, 0.f);
            v.y = fmaxf(acc[i][1] + b4.y, 0.f);
            v.z = fmaxf(acc[i][2] + b4.z, 0.f);
            v.w = fmaxf(acc[i][3] + b4.w, 0.f);
            *(float4*)(out + (size_t)gr * 256 + lane * 4) = v;
        }
    }
}

extern "C" void kernel_launch(void* const* d_in, const int* in_sizes, int n_in,
                              void* d_out, int out_size, void* d_ws, size_t ws_size,
                              hipStream_t stream) {
    const float* x   = (const float*)d_in[0];
    const int* edge  = (const int*)d_in[1];
    const float* Wl0 = (const float*)d_in[2];
    const float* bl0 = (const float*)d_in[3];
    const float* Wr0 = (const float*)d_in[4];
    const float* Wl1 = (const float*)d_in[5];
    const float* bl1 = (const float*)d_in[6];
    const float* Wr1 = (const float*)d_in[7];
    const float* Wl2 = (const float*)d_in[8];
    const float* bl2 = (const float*)d_in[9];
    const float* Wr2 = (const float*)d_in[10];

    int n = in_sizes[0] / 128;   // 50000
    int E = in_sizes[1] / 2;     // 800000
    const int* src = edge;
    const int* dst = edge + E;

    char* w = (char*)d_ws;
    auto alloc = [&](size_t bytes) { char* p = w; w += align_up(bytes, 256); return p; };
    int*   deg    = (int*)alloc((size_t)n * 4);
    int*   rowptr = (int*)alloc(((size_t)n + 1) * 4);
    int*   cursor = (int*)alloc((size_t)n * 4);
    int*   csr    = (int*)alloc((size_t)E * 4);
    float* invd   = (float*)alloc((size_t)n * 4);
    float* aggs   = (float*)alloc((size_t)n * 256 * 4);
    float* h1     = (float*)alloc((size_t)n * 256 * 4);
    float* h0     = (float*)d_out;   // reused: fully rewritten by final layer

    hipMemsetAsync(deg, 0, (size_t)n * 4, stream);
    deg_kernel<<<(E + 255) / 256, 256, 0, stream>>>(dst, deg, E);
    scan_kernel<<<1, 1024, 0, stream>>>(deg, rowptr, cursor, invd, n);
    fill_kernel<<<(E + 255) / 256, 256, 0, stream>>>(src, dst, cursor, csr, E);

    int gemm_grid = (n + 63) / 64;
    // layer 0: C=128 -> 256
    agg_kernel<128><<<n, 128, 0, stream>>>(x, rowptr, csr, invd, aggs);
    gemm_fused<128><<<gemm_grid, 256, 0, stream>>>(aggs, x, Wl0, Wr0, bl0, h0, n);
    // layer 1: 256 -> 256
    agg_kernel<256><<<n, 256, 0, stream>>>(h0, rowptr, csr, invd, aggs);
    gemm_fused<256><<<gemm_grid, 256, 0, stream>>>(aggs, h0, Wl1, Wr1, bl1, h1, n);
    // layer 2: 256 -> 256
    agg_kernel<256><<<n, 256, 0, stream>>>(h1, rowptr, csr, invd, aggs);
    gemm_fused<256><<<gemm_grid, 256, 0, stream>>>(aggs, h1, Wl2, Wr2, bl2, (float*)d_out, n);
}

// Round 2
// 2126.142 us; speedup vs baseline: 1.0110x; 1.0110x over previous
//
#include <hip/hip_runtime.h>
#include <cstdint>
#include <cstddef>

// GraphSAGE 3-layer, mean aggregation, fp32.
// R1 fix: gemm_fused was spilling acc[16][4] (VGPR_Count=64, 1.5GB scratch
// writes/dispatch, VALUBusy 24%). __launch_bounds__(256,4) -> 128 VGPR cap,
// matches the 4-block/CU LDS limit (40KB/block).

static inline size_t align_up(size_t x, size_t a) { return (x + a - 1) / a * a; }

__global__ void deg_kernel(const int* __restrict__ dst, int* __restrict__ deg, int E) {
    int i = blockIdx.x * blockDim.x + threadIdx.x;
    if (i < E) atomicAdd(&deg[dst[i]], 1);
}

// Single block, 1024 threads: chunked exclusive scan of deg -> rowptr, cursor, inv_deg.
__global__ void scan_kernel(const int* __restrict__ deg, int* __restrict__ rowptr,
                            int* __restrict__ cursor, float* __restrict__ inv_deg, int n) {
    __shared__ int sums[1024];
    int tid = threadIdx.x;
    int chunk = (n + 1023) >> 10;
    int start = tid * chunk;
    int end = min(start + chunk, n);
    if (start > n) { start = n; end = n; }
    int s = 0;
    for (int i = start; i < end; ++i) s += deg[i];
    sums[tid] = s;
    __syncthreads();
    for (int off = 1; off < 1024; off <<= 1) {
        int v = (tid >= off) ? sums[tid - off] : 0;
        __syncthreads();
        sums[tid] += v;
        __syncthreads();
    }
    int run = sums[tid] - s;  // exclusive prefix for this chunk
    for (int i = start; i < end; ++i) {
        int d = deg[i];
        rowptr[i] = run;
        cursor[i] = run;
        inv_deg[i] = d > 0 ? 1.0f / (float)d : 0.0f;
        run += d;
    }
    if (tid == 1023) rowptr[n] = run;
}

__global__ void fill_kernel(const int* __restrict__ src, const int* __restrict__ dst,
                            int* __restrict__ cursor, int* __restrict__ csr, int E) {
    int i = blockIdx.x * blockDim.x + threadIdx.x;
    if (i < E) {
        int p = atomicAdd(&cursor[dst[i]], 1);
        csr[p] = src[i];
    }
}

// One block per node; thread t owns feature t. 4-way unrolled gather-sum.
template<int C>
__global__ void agg_kernel(const float* __restrict__ h, const int* __restrict__ rowptr,
                           const int* __restrict__ csr, const float* __restrict__ inv_deg,
                           float* __restrict__ aggs) {
    int node = blockIdx.x;
    int t = threadIdx.x;
    int b = rowptr[node], e = rowptr[node + 1];
    float a0 = 0.f, a1 = 0.f, a2 = 0.f, a3 = 0.f;
    int k = b;
    for (; k + 3 < e; k += 4) {
        int s0 = csr[k], s1 = csr[k + 1], s2 = csr[k + 2], s3 = csr[k + 3];
        a0 += h[(size_t)s0 * C + t];
        a1 += h[(size_t)s1 * C + t];
        a2 += h[(size_t)s2 * C + t];
        a3 += h[(size_t)s3 * C + t];
    }
    for (; k < e; ++k) a0 += h[(size_t)csr[k] * C + t];
    aggs[(size_t)node * C + t] = ((a0 + a1) + (a2 + a3)) * inv_deg[node];
}

// out[i,c] = relu( sum_k A1[i,k]*W1[k,c] + sum_k A2[i,k]*W2[k,c] + bias[c] )
// BM=64 rows x BN=256 cols per block, BK=32. 256 threads: wave w handles rows
// w*16..w*16+15; lane owns 4 consecutive cols. A-reads broadcast, W-reads
// lane-consecutive b128 (conflict-free).
template<int K1>
__global__ __launch_bounds__(256, 4)
void gemm_fused(const float* __restrict__ A1, const float* __restrict__ A2,
                const float* __restrict__ W1, const float* __restrict__ W2,
                const float* __restrict__ bias, float* __restrict__ out, int n) {
    constexpr int BM = 64, BK = 32;
    __shared__ float As[BM * BK];    // 8 KB
    __shared__ float Ws[BK * 256];   // 32 KB
    int tid = threadIdx.x;
    int lane = tid & 63;
    int wave = tid >> 6;
    int row0 = blockIdx.x * BM;

    float acc[16][4];
    #pragma unroll
    for (int i = 0; i < 16; ++i)
        #pragma unroll
        for (int j = 0; j < 4; ++j) acc[i][j] = 0.f;

    constexpr int NT = (2 * K1) / BK;
    #pragma unroll 1
    for (int kt = 0; kt < NT; ++kt) {
        int kg = kt * BK;
        const float* A = (kg < K1) ? A1 : A2;
        const float* W = (kg < K1) ? W1 : W2;
        int kofs = (kg < K1) ? kg : (kg - K1);
        // stage A tile: 64x32 floats, 2 float4 per thread
        {
            int r = tid >> 3;               // 0..31
            int k4 = (tid & 7) * 4;
            #pragma unroll
            for (int p = 0; p < 2; ++p) {
                int row = r + p * 32;
                float4 v = make_float4(0.f, 0.f, 0.f, 0.f);
                int gr = row0 + row;
                if (gr < n) v = *(const float4*)(A + (size_t)gr * K1 + kofs + k4);
                *(float4*)(As + row * BK + k4) = v;
            }
        }
        // stage W tile: 32x256 floats, 8 float4 per thread (per wave: one k-row, contiguous)
        {
            int c4 = (tid & 63) * 4;
            int kk = tid >> 6;              // 0..3
            #pragma unroll
            for (int p = 0; p < 8; ++p) {
                int k = kk + p * 4;
                *(float4*)(Ws + k * 256 + c4) = *(const float4*)(W + (size_t)(kofs + k) * 256 + c4);
            }
        }
        __syncthreads();
        const float4* As4 = (const float4*)As;
        const float4* Ws4 = (const float4*)Ws;
        #pragma unroll
        for (int kb = 0; kb < 8; ++kb) {
            float4 w0 = Ws4[(kb * 4 + 0) * 64 + lane];
            float4 w1 = Ws4[(kb * 4 + 1) * 64 + lane];
            float4 w2 = Ws4[(kb * 4 + 2) * 64 + lane];
            float4 w3 = Ws4[(kb * 4 + 3) * 64 + lane];
            #pragma unroll
            for (int i = 0; i < 16; ++i) {
                float4 a = As4[(wave * 16 + i) * 8 + kb];
                acc[i][0] += a.x * w0.x; acc[i][1] += a.x * w0.y; acc[i][2] += a.x * w0.z; acc[i][3] += a.x * w0.w;
                acc[i][0] += a.y * w1.x; acc[i][1] += a.y * w1.y; acc[i][2] += a.y * w1.z; acc[i][3] += a.y * w1.w;
                acc[i][0] += a.z * w2.x; acc[i][1] += a.z * w2.y; acc[i][2] += a.z * w2.z; acc[i][3] += a.z * w2.w;
                acc[i][0] += a.w * w3.x; acc[i][1] += a.w * w3.y; acc[i][2] += a.w * w3.z; acc[i][3] += a.w * w3.w;
            }
        }
        __syncthreads();
    }

    float4 b4 = *(const float4*)(bias + lane * 4);
    #pragma unroll
    for (int i = 0; i < 16; ++i) {
        int gr = row0 + wave * 16 + i;
        if (gr < n) {
            float4 v;
            v.x = fmaxf(acc[i][0] + b4.x, 0.f);
            v.y = fmaxf(acc[i][1] + b4.y, 0.f);
            v.z = fmaxf(acc[i][2] + b4.z, 0.f);
            v.w = fmaxf(acc[i][3] + b4.w, 0.f);
            *(float4*)(out + (size_t)gr * 256 + lane * 4) = v;
        }
    }
}

extern "C" void kernel_launch(void* const* d_in, const int* in_sizes, int n_in,
                              void* d_out, int out_size, void* d_ws, size_t ws_size,
                              hipStream_t stream) {
    const float* x   = (const float*)d_in[0];
    const int* edge  = (const int*)d_in[1];
    const float* Wl0 = (const float*)d_in[2];
    const float* bl0 = (const float*)d_in[3];
    const float* Wr0 = (const float*)d_in[4];
    const float* Wl1 = (const float*)d_in[5];
    const float* bl1 = (const float*)d_in[6];
    const float* Wr1 = (const float*)d_in[7];
    const float* Wl2 = (const float*)d_in[8];
    const float* bl2 = (const float*)d_in[9];
    const float* Wr2 = (const float*)d_in[10];

    int n = in_sizes[0] / 128;   // 50000
    int E = in_sizes[1] / 2;     // 800000
    const int* src = edge;
    const int* dst = edge + E;

    char* w = (char*)d_ws;
    auto alloc = [&](size_t bytes) { char* p = w; w += align_up(bytes, 256); return p; };
    int*   deg    = (int*)alloc((size_t)n * 4);
    int*   rowptr = (int*)alloc(((size_t)n + 1) * 4);
    int*   cursor = (int*)alloc((size_t)n * 4);
    int*   csr    = (int*)alloc((size_t)E * 4);
    float* invd   = (float*)alloc((size_t)n * 4);
    float* aggs   = (float*)alloc((size_t)n * 256 * 4);
    float* h1     = (float*)alloc((size_t)n * 256 * 4);
    float* h0     = (float*)d_out;   // reused: fully rewritten by final layer

    hipMemsetAsync(deg, 0, (size_t)n * 4, stream);
    deg_kernel<<<(E + 255) / 256, 256, 0, stream>>>(dst, deg, E);
    scan_kernel<<<1, 1024, 0, stream>>>(deg, rowptr, cursor, invd, n);
    fill_kernel<<<(E + 255) / 256, 256, 0, stream>>>(src, dst, cursor, csr, E);

    int gemm_grid = (n + 63) / 64;
    // layer 0: C=128 -> 256
    agg_kernel<128><<<n, 128, 0, stream>>>(x, rowptr, csr, invd, aggs);
    gemm_fused<128><<<gemm_grid, 256, 0, stream>>>(aggs, x, Wl0, Wr0, bl0, h0, n);
    // layer 1: 256 -> 256
    agg_kernel<256><<<n, 256, 0, stream>>>(h0, rowptr, csr, invd, aggs);
    gemm_fused<256><<<gemm_grid, 256, 0, stream>>>(aggs, h0, Wl1, Wr1, bl1, h1, n);
    // layer 2: 256 -> 256
    agg_kernel<256><<<n, 256, 0, stream>>>(h1, rowptr, csr, invd, aggs);
    gemm_fused<256><<<gemm_grid, 256, 0, stream>>>(aggs, h1, Wl2, Wr2, bl2, (float*)d_out, n);
}

// Round 3
// 715.943 us; speedup vs baseline: 3.0025x; 2.9697x over previous
//
#include <hip/hip_runtime.h>
#include <cstdint>
#include <cstddef>

// GraphSAGE 3-layer, mean aggregation.
// R2: GEMMs moved to split-bf16 MFMA (hi/lo decomposition, 3 mfma per frag,
// err ~2^-16). fp32 scalar GEMM was spilling at VGPR=64 (1.5GB scratch traffic).
// W pre-converted once per layer into k-step-blocked, XOR-swizzled bf16 hi/lo
// planes so GEMM W staging is a pure b128 copy and all frag ds_reads are
// bank-conflict-free. A (aggs/h, fp32) is split in-register during staging.

typedef __bf16 bf16x8 __attribute__((ext_vector_type(8)));
typedef __bf16 bf16x4 __attribute__((ext_vector_type(4)));
typedef float  f32x4  __attribute__((ext_vector_type(4)));

static inline size_t align_up(size_t x, size_t a) { return (x + a - 1) / a * a; }

__global__ void deg_kernel(const int* __restrict__ dst, int* __restrict__ deg, int E) {
    int i = blockIdx.x * blockDim.x + threadIdx.x;
    if (i < E) atomicAdd(&deg[dst[i]], 1);
}

// Single block, 1024 threads: chunked exclusive scan of deg -> rowptr, cursor, inv_deg.
__global__ void scan_kernel(const int* __restrict__ deg, int* __restrict__ rowptr,
                            int* __restrict__ cursor, float* __restrict__ inv_deg, int n) {
    __shared__ int sums[1024];
    int tid = threadIdx.x;
    int chunk = (n + 1023) >> 10;
    int start = tid * chunk;
    int end = min(start + chunk, n);
    if (start > n) { start = n; end = n; }
    int s = 0;
    for (int i = start; i < end; ++i) s += deg[i];
    sums[tid] = s;
    __syncthreads();
    for (int off = 1; off < 1024; off <<= 1) {
        int v = (tid >= off) ? sums[tid - off] : 0;
        __syncthreads();
        sums[tid] += v;
        __syncthreads();
    }
    int run = sums[tid] - s;
    for (int i = start; i < end; ++i) {
        int d = deg[i];
        rowptr[i] = run;
        cursor[i] = run;
        inv_deg[i] = d > 0 ? 1.0f / (float)d : 0.0f;
        run += d;
    }
    if (tid == 1023) rowptr[n] = run;
}

__global__ void fill_kernel(const int* __restrict__ src, const int* __restrict__ dst,
                            int* __restrict__ cursor, int* __restrict__ csr, int E) {
    int i = blockIdx.x * blockDim.x + threadIdx.x;
    if (i < E) {
        int p = atomicAdd(&cursor[dst[i]], 1);
        csr[p] = src[i];
    }
}

// One block per node; thread t owns feature t. 4-way unrolled gather-sum.
template<int C>
__global__ void agg_kernel(const float* __restrict__ h, const int* __restrict__ rowptr,
                           const int* __restrict__ csr, const float* __restrict__ inv_deg,
                           float* __restrict__ aggs) {
    int node = blockIdx.x;
    int t = threadIdx.x;
    int b = rowptr[node], e = rowptr[node + 1];
    float a0 = 0.f, a1 = 0.f, a2 = 0.f, a3 = 0.f;
    int k = b;
    for (; k + 3 < e; k += 4) {
        int s0 = csr[k], s1 = csr[k + 1], s2 = csr[k + 2], s3 = csr[k + 3];
        a0 += h[(size_t)s0 * C + t];
        a1 += h[(size_t)s1 * C + t];
        a2 += h[(size_t)s2 * C + t];
        a3 += h[(size_t)s3 * C + t];
    }
    for (; k < e; ++k) a0 += h[(size_t)csr[k] * C + t];
    aggs[(size_t)node * C + t] = ((a0 + a1) + (a2 + a3)) * inv_deg[node];
}

// Pre-convert W = [Wl; Wr] (fp32, [K1][256] each) into per-k-step tiles:
// step s (BK=32): [hi 16KB][lo 16KB], element (k,n) at byte
// ((n*32 + k%32)*2) ^ ((n&7)<<4)  -> W^T-ish [n][kk] layout, XOR-swizzled so
// GEMM frag ds_read_b128 is bank-conflict-free. One block per 4-k group.
__global__ void convert_w(const float* __restrict__ Wl, const float* __restrict__ Wr,
                          uint8_t* __restrict__ Wpre, int K1) {
    int n = threadIdx.x;        // 0..255
    int kbase = blockIdx.x * 4; // 4 consecutive k per block
    bf16x4 hi4, lo4;
    #pragma unroll
    for (int j = 0; j < 4; ++j) {
        int k = kbase + j;
        float w = (k < K1) ? Wl[(size_t)k * 256 + n] : Wr[(size_t)(k - K1) * 256 + n];
        __bf16 h = (__bf16)w;
        __bf16 l = (__bf16)(w - (float)h);
        hi4[j] = h;
        lo4[j] = l;
    }
    int s = kbase >> 5;
    int kk = kbase & 31;
    uint32_t byte = (uint32_t)((n * 32 + kk) * 2) ^ (uint32_t)((n & 7) << 4);
    *(bf16x4*)(Wpre + (size_t)s * 32768 + byte) = hi4;
    *(bf16x4*)(Wpre + (size_t)s * 32768 + 16384 + byte) = lo4;
}

// Fused GEMM: out = relu([A1 | A2] @ Wpre + bias), A1/A2 fp32 [n][K1].
// BM=64, BN=256, BK=32. 256 threads = 4 waves; wave w owns cols w*64..w*64+63.
// Per wave: 16 output frags (4 mt x 4 nt), 3 mfma each (hi*hi, lo*hi, hi*lo).
template<int K1>
__global__ __launch_bounds__(256, 2)
void gemm_mfma(const float* __restrict__ A1, const float* __restrict__ A2,
               const uint8_t* __restrict__ Wpre, const float* __restrict__ bias,
               float* __restrict__ out, int n) {
    __shared__ __align__(16) uint8_t lds[4096 * 2 + 32768];
    uint8_t* lds_ahi = lds;          // 64x32 bf16 = 4KB
    uint8_t* lds_alo = lds + 4096;   // 4KB
    uint8_t* lds_w   = lds + 8192;   // [hi 16KB][lo 16KB]

    const int tid = threadIdx.x;
    const int l = tid & 63;
    const int w = tid >> 6;
    const int lr = l & 15;
    const int lg = l >> 4;
    const int row0 = blockIdx.x * 64;
    const int wn = w * 64;

    f32x4 acc[4][4];
    #pragma unroll
    for (int mt = 0; mt < 4; ++mt)
        #pragma unroll
        for (int nt = 0; nt < 4; ++nt)
            acc[mt][nt] = (f32x4)(0.f);

    // per-thread frag byte offsets (constant across k-steps)
    uint32_t abyte[4], bbyte[4];
    #pragma unroll
    for (int mt = 0; mt < 4; ++mt) {
        int row = mt * 16 + lr;
        abyte[mt] = (uint32_t)(row * 64 + lg * 16) ^ (uint32_t)((lr & 7) << 4);
    }
    #pragma unroll
    for (int nt = 0; nt < 4; ++nt) {
        int nn = wn + nt * 16 + lr;
        bbyte[nt] = (uint32_t)(nn * 64 + lg * 16) ^ (uint32_t)((lr & 7) << 4);
    }

    // A staging map: idx = tid + p*256 -> row = idx>>3 (0..63), k = (idx&7)*4
    const int S1 = K1 / 32;
    #pragma unroll 1
    for (int s = 0; s < 2 * S1; ++s) {
        const float* __restrict__ A = (s < S1) ? A1 : A2;
        const int k0 = ((s < S1) ? s : s - S1) * 32;

        // stage A tile 64x32 fp32 -> split -> LDS hi/lo (swizzled)
        #pragma unroll
        for (int p = 0; p < 2; ++p) {
            int idx = tid + p * 256;
            int r = idx >> 3;
            int k = (idx & 7) * 4;
            int gr = row0 + r;
            float4 v = make_float4(0.f, 0.f, 0.f, 0.f);
            if (gr < n) v = *(const float4*)(A + (size_t)gr * K1 + k0 + k);
            bf16x4 h4, l4;
            float vv[4] = {v.x, v.y, v.z, v.w};
            #pragma unroll
            for (int j = 0; j < 4; ++j) {
                __bf16 h = (__bf16)vv[j];
                h4[j] = h;
                l4[j] = (__bf16)(vv[j] - (float)h);
            }
            uint32_t byte = (uint32_t)(r * 64 + k * 2) ^ (uint32_t)((r & 7) << 4);
            *(bf16x4*)(lds_ahi + byte) = h4;
            *(bf16x4*)(lds_alo + byte) = l4;
        }
        // stage W tiles: pure 16B copy, already in final (swizzled) order
        {
            const uint8_t* __restrict__ Wstep = Wpre + (size_t)s * 32768;
            #pragma unroll
            for (int c = 0; c < 8; ++c) {
                int chunk = tid + c * 256;
                *(uint4*)(lds_w + chunk * 16) = *(const uint4*)(Wstep + chunk * 16);
            }
        }
        __syncthreads();

        bf16x8 ahi[4], alo[4], bhi[4], blo[4];
        #pragma unroll
        for (int mt = 0; mt < 4; ++mt) {
            ahi[mt] = *(const bf16x8*)(lds_ahi + abyte[mt]);
            alo[mt] = *(const bf16x8*)(lds_alo + abyte[mt]);
        }
        #pragma unroll
        for (int nt = 0; nt < 4; ++nt) {
            bhi[nt] = *(const bf16x8*)(lds_w + bbyte[nt]);
            blo[nt] = *(const bf16x8*)(lds_w + 16384 + bbyte[nt]);
        }
        #pragma unroll
        for (int mt = 0; mt < 4; ++mt)
            #pragma unroll
            for (int nt = 0; nt < 4; ++nt) {
                acc[mt][nt] = __builtin_amdgcn_mfma_f32_16x16x32_bf16(ahi[mt], bhi[nt], acc[mt][nt], 0, 0, 0);
                acc[mt][nt] = __builtin_amdgcn_mfma_f32_16x16x32_bf16(alo[mt], bhi[nt], acc[mt][nt], 0, 0, 0);
                acc[mt][nt] = __builtin_amdgcn_mfma_f32_16x16x32_bf16(ahi[mt], blo[nt], acc[mt][nt], 0, 0, 0);
            }
        __syncthreads();
    }

    // epilogue: D row = mt*16 + lg*4 + rr, col = wn + nt*16 + lr (m89-verified)
    #pragma unroll
    for (int nt = 0; nt < 4; ++nt) {
        int col = wn + nt * 16 + lr;
        float bv = bias[col];
        #pragma unroll
        for (int mt = 0; mt < 4; ++mt) {
            #pragma unroll
            for (int rr = 0; rr < 4; ++rr) {
                int grow = row0 + mt * 16 + lg * 4 + rr;
                if (grow < n)
                    out[(size_t)grow * 256 + col] = fmaxf(acc[mt][nt][rr] + bv, 0.f);
            }
        }
    }
}

extern "C" void kernel_launch(void* const* d_in, const int* in_sizes, int n_in,
                              void* d_out, int out_size, void* d_ws, size_t ws_size,
                              hipStream_t stream) {
    const float* x   = (const float*)d_in[0];
    const int* edge  = (const int*)d_in[1];
    const float* Wl0 = (const float*)d_in[2];
    const float* bl0 = (const float*)d_in[3];
    const float* Wr0 = (const float*)d_in[4];
    const float* Wl1 = (const float*)d_in[5];
    const float* bl1 = (const float*)d_in[6];
    const float* Wr1 = (const float*)d_in[7];
    const float* Wl2 = (const float*)d_in[8];
    const float* bl2 = (const float*)d_in[9];
    const float* Wr2 = (const float*)d_in[10];

    int n = in_sizes[0] / 128;   // 50000
    int E = in_sizes[1] / 2;     // 800000
    const int* src = edge;
    const int* dst = edge + E;

    char* wptr = (char*)d_ws;
    auto alloc = [&](size_t bytes) { char* p = wptr; wptr += align_up(bytes, 256); return p; };
    int*     deg    = (int*)alloc((size_t)n * 4);
    int*     rowptr = (int*)alloc(((size_t)n + 1) * 4);
    int*     cursor = (int*)alloc((size_t)n * 4);
    int*     csr    = (int*)alloc((size_t)E * 4);
    float*   invd   = (float*)alloc((size_t)n * 4);
    uint8_t* Wp0    = (uint8_t*)alloc(8 * 32768);    // 256KB (K=256)
    uint8_t* Wp1    = (uint8_t*)alloc(16 * 32768);   // 512KB (K=512)
    uint8_t* Wp2    = (uint8_t*)alloc(16 * 32768);   // 512KB
    float*   aggs   = (float*)alloc((size_t)n * 256 * 4);
    float*   h1     = (float*)alloc((size_t)n * 256 * 4);
    float*   h0     = (float*)d_out;   // reused: fully rewritten by final layer

    hipMemsetAsync(deg, 0, (size_t)n * 4, stream);
    deg_kernel<<<(E + 255) / 256, 256, 0, stream>>>(dst, deg, E);
    scan_kernel<<<1, 1024, 0, stream>>>(deg, rowptr, cursor, invd, n);
    fill_kernel<<<(E + 255) / 256, 256, 0, stream>>>(src, dst, cursor, csr, E);

    convert_w<<<2 * 128 / 4, 256, 0, stream>>>(Wl0, Wr0, Wp0, 128);
    convert_w<<<2 * 256 / 4, 256, 0, stream>>>(Wl1, Wr1, Wp1, 256);
    convert_w<<<2 * 256 / 4, 256, 0, stream>>>(Wl2, Wr2, Wp2, 256);

    int gemm_grid = (n + 63) / 64;   // 782
    // layer 0: C=128 -> 256
    agg_kernel<128><<<n, 128, 0, stream>>>(x, rowptr, csr, invd, aggs);
    gemm_mfma<128><<<gemm_grid, 256, 0, stream>>>(aggs, x, Wp0, bl0, h0, n);
    // layer 1: 256 -> 256
    agg_kernel<256><<<n, 256, 0, stream>>>(h0, rowptr, csr, invd, aggs);
    gemm_mfma<256><<<gemm_grid, 256, 0, stream>>>(aggs, h0, Wp1, bl1, h1, n);
    // layer 2: 256 -> 256
    agg_kernel<256><<<n, 256, 0, stream>>>(h1, rowptr, csr, invd, aggs);
    gemm_mfma<256><<<gemm_grid, 256, 0, stream>>>(aggs, h1, Wp2, bl2, (float*)d_out, n);
}

// Round 4
// 599.438 us; speedup vs baseline: 3.5861x; 1.1944x over previous
//
#include <hip/hip_runtime.h>
#include <cstdint>
#include <cstddef>

// GraphSAGE 3-layer, mean aggregation.
// R3: scan_kernel was 133us (single block = one CU, latency-bound, 18% of total).
// Replaced with 3-phase multi-block scan (~10us). agg_kernel vectorized to
// float4 per lane (C/4 lanes per node) for 4x fewer loads + deeper MLP.
// GEMM (split-bf16 MFMA, R2) unchanged.

typedef __bf16 bf16x8 __attribute__((ext_vector_type(8)));
typedef __bf16 bf16x4 __attribute__((ext_vector_type(4)));
typedef float  f32x4  __attribute__((ext_vector_type(4)));

static inline size_t align_up(size_t x, size_t a) { return (x + a - 1) / a * a; }

__global__ void deg_kernel(const int* __restrict__ dst, int* __restrict__ deg, int E) {
    int i = blockIdx.x * blockDim.x + threadIdx.x;
    if (i < E) atomicAdd(&deg[dst[i]], 1);
}

// ---- 3-phase scan: deg -> rowptr (exclusive), cursor, inv_deg ----
// phase A: per-block (1024 elems) sums
__global__ void scan_a(const int* __restrict__ deg, int* __restrict__ blocksums, int n) {
    __shared__ int ts[256];
    int t = threadIdx.x;
    int base = blockIdx.x * 1024 + t * 4;
    int s = 0;
    #pragma unroll
    for (int j = 0; j < 4; ++j) if (base + j < n) s += deg[base + j];
    ts[t] = s;
    __syncthreads();
    #pragma unroll
    for (int off = 128; off >= 1; off >>= 1) {
        if (t < off) ts[t] += ts[t + off];
        __syncthreads();
    }
    if (t == 0) blocksums[blockIdx.x] = ts[0];
}

// phase B: single small block scans blocksums (NB <= 256), writes rowptr[n]=E
__global__ void scan_b(const int* __restrict__ blocksums, int* __restrict__ blockoff,
                       int NB, int* __restrict__ rowptr_n) {
    __shared__ int ts[256];
    int t = threadIdx.x;
    int v = (t < NB) ? blocksums[t] : 0;
    ts[t] = v;
    __syncthreads();
    for (int off = 1; off < 256; off <<= 1) {
        int u = (t >= off) ? ts[t - off] : 0;
        __syncthreads();
        ts[t] += u;
        __syncthreads();
    }
    if (t < NB) blockoff[t] = ts[t] - v;
    if (t == 255) *rowptr_n = ts[255];
}

// phase C: per-block local scan + global offset -> rowptr, cursor, inv_deg
__global__ void scan_c(const int* __restrict__ deg, const int* __restrict__ blockoff,
                       int* __restrict__ rowptr, int* __restrict__ cursor,
                       float* __restrict__ inv_deg, int n) {
    __shared__ int ts[256];
    int t = threadIdx.x;
    int base = blockIdx.x * 1024 + t * 4;
    int d[4];
    int s = 0;
    #pragma unroll
    for (int j = 0; j < 4; ++j) {
        d[j] = (base + j < n) ? deg[base + j] : 0;
        s += d[j];
    }
    ts[t] = s;
    __syncthreads();
    for (int off = 1; off < 256; off <<= 1) {
        int u = (t >= off) ? ts[t - off] : 0;
        __syncthreads();
        ts[t] += u;
        __syncthreads();
    }
    int ex = ts[t] - s + blockoff[blockIdx.x];
    #pragma unroll
    for (int j = 0; j < 4; ++j) {
        if (base + j < n) {
            rowptr[base + j] = ex;
            cursor[base + j] = ex;
            inv_deg[base + j] = d[j] > 0 ? 1.0f / (float)d[j] : 0.0f;
            ex += d[j];
        }
    }
}

__global__ void fill_kernel(const int* __restrict__ src, const int* __restrict__ dst,
                            int* __restrict__ cursor, int* __restrict__ csr, int E) {
    int i = blockIdx.x * blockDim.x + threadIdx.x;
    if (i < E) {
        int p = atomicAdd(&cursor[dst[i]], 1);
        csr[p] = src[i];
    }
}

// Vectorized aggregation: C/4 lanes per node, each lane owns a float4 column
// slice. 4-deep neighbor unroll for MLP. 256 threads/block.
template<int C>
__global__ void agg_kernel(const float* __restrict__ h, const int* __restrict__ rowptr,
                           const int* __restrict__ csr, const float* __restrict__ inv_deg,
                           float* __restrict__ aggs) {
    constexpr int LPN = C / 4;       // lanes per node
    constexpr int NPB = 256 / LPN;   // nodes per block
    int node = blockIdx.x * NPB + (int)(threadIdx.x / LPN);
    if (node >= 50000 * 2) return;   // safety; real bound checked below
    int sub = threadIdx.x % LPN;
    int nmax = gridDim.x * NPB;      // not used; bound via rowptr guard
    (void)nmax;
    if (node >= (int)gridDim.y) {}   // no-op
    // real guard:
    // (n passed via gridDim trick avoided; caller sizes grid so node<n except tail)
    // tail guard below using rowptr requires node<n; pass n in last arg instead.
    // -- replaced: see n_arg version
    int b = rowptr[node], e = rowptr[node + 1];
    f32x4 a0 = (f32x4)(0.f), a1 = (f32x4)(0.f), a2 = (f32x4)(0.f), a3 = (f32x4)(0.f);
    const float4* h4 = (const float4*)h;
    int k = b;
    for (; k + 3 < e; k += 4) {
        int s0 = csr[k], s1 = csr[k + 1], s2 = csr[k + 2], s3 = csr[k + 3];
        float4 v0 = h4[(size_t)s0 * LPN + sub];
        float4 v1 = h4[(size_t)s1 * LPN + sub];
        float4 v2 = h4[(size_t)s2 * LPN + sub];
        float4 v3 = h4[(size_t)s3 * LPN + sub];
        a0 += (f32x4){v0.x, v0.y, v0.z, v0.w};
        a1 += (f32x4){v1.x, v1.y, v1.z, v1.w};
        a2 += (f32x4){v2.x, v2.y, v2.z, v2.w};
        a3 += (f32x4){v3.x, v3.y, v3.z, v3.w};
    }
    for (; k < e; ++k) {
        float4 v0 = h4[(size_t)csr[k] * LPN + sub];
        a0 += (f32x4){v0.x, v0.y, v0.z, v0.w};
    }
    f32x4 r = ((a0 + a1) + (a2 + a3)) * inv_deg[node];
    *(float4*)(aggs + (size_t)node * C + sub * 4) = (float4){r[0], r[1], r[2], r[3]};
}

// guarded wrapper launch helper (node < n): we size the grid exactly and n is a
// multiple of NPB tail-safe via an explicit check kernel parameter; to keep the
// template simple we pad: caller guarantees rowptr[node+1] valid only for
// node<n, so we pass n and guard.
template<int C>
__global__ void agg_kernel_n(const float* __restrict__ h, const int* __restrict__ rowptr,
                             const int* __restrict__ csr, const float* __restrict__ inv_deg,
                             float* __restrict__ aggs, int n) {
    constexpr int LPN = C / 4;
    constexpr int NPB = 256 / LPN;
    int node = blockIdx.x * NPB + (int)(threadIdx.x / LPN);
    if (node >= n) return;
    int sub = threadIdx.x % LPN;
    int b = rowptr[node], e = rowptr[node + 1];
    f32x4 a0 = (f32x4)(0.f), a1 = (f32x4)(0.f), a2 = (f32x4)(0.f), a3 = (f32x4)(0.f);
    const float4* h4 = (const float4*)h;
    int k = b;
    for (; k + 3 < e; k += 4) {
        int s0 = csr[k], s1 = csr[k + 1], s2 = csr[k + 2], s3 = csr[k + 3];
        float4 v0 = h4[(size_t)s0 * LPN + sub];
        float4 v1 = h4[(size_t)s1 * LPN + sub];
        float4 v2 = h4[(size_t)s2 * LPN + sub];
        float4 v3 = h4[(size_t)s3 * LPN + sub];
        a0 += (f32x4){v0.x, v0.y, v0.z, v0.w};
        a1 += (f32x4){v1.x, v1.y, v1.z, v1.w};
        a2 += (f32x4){v2.x, v2.y, v2.z, v2.w};
        a3 += (f32x4){v3.x, v3.y, v3.z, v3.w};
    }
    for (; k < e; ++k) {
        float4 v0 = h4[(size_t)csr[k] * LPN + sub];
        a0 += (f32x4){v0.x, v0.y, v0.z, v0.w};
    }
    f32x4 r = ((a0 + a1) + (a2 + a3)) * inv_deg[node];
    *(float4*)(aggs + (size_t)node * C + sub * 4) = (float4){r[0], r[1], r[2], r[3]};
}

// Pre-convert W = [Wl; Wr] into per-k-step swizzled bf16 hi/lo planes.
__global__ void convert_w(const float* __restrict__ Wl, const float* __restrict__ Wr,
                          uint8_t* __restrict__ Wpre, int K1) {
    int n = threadIdx.x;
    int kbase = blockIdx.x * 4;
    bf16x4 hi4, lo4;
    #pragma unroll
    for (int j = 0; j < 4; ++j) {
        int k = kbase + j;
        float w = (k < K1) ? Wl[(size_t)k * 256 + n] : Wr[(size_t)(k - K1) * 256 + n];
        __bf16 h = (__bf16)w;
        __bf16 l = (__bf16)(w - (float)h);
        hi4[j] = h;
        lo4[j] = l;
    }
    int s = kbase >> 5;
    int kk = kbase & 31;
    uint32_t byte = (uint32_t)((n * 32 + kk) * 2) ^ (uint32_t)((n & 7) << 4);
    *(bf16x4*)(Wpre + (size_t)s * 32768 + byte) = hi4;
    *(bf16x4*)(Wpre + (size_t)s * 32768 + 16384 + byte) = lo4;
}

// Fused GEMM: out = relu([A1 | A2] @ Wpre + bias). Split-bf16, 3 mfma/frag.
template<int K1>
__global__ __launch_bounds__(256, 2)
void gemm_mfma(const float* __restrict__ A1, const float* __restrict__ A2,
               const uint8_t* __restrict__ Wpre, const float* __restrict__ bias,
               float* __restrict__ out, int n) {
    __shared__ __align__(16) uint8_t lds[4096 * 2 + 32768];
    uint8_t* lds_ahi = lds;
    uint8_t* lds_alo = lds + 4096;
    uint8_t* lds_w   = lds + 8192;

    const int tid = threadIdx.x;
    const int l = tid & 63;
    const int w = tid >> 6;
    const int lr = l & 15;
    const int lg = l >> 4;
    const int row0 = blockIdx.x * 64;
    const int wn = w * 64;

    f32x4 acc[4][4];
    #pragma unroll
    for (int mt = 0; mt < 4; ++mt)
        #pragma unroll
        for (int nt = 0; nt < 4; ++nt)
            acc[mt][nt] = (f32x4)(0.f);

    uint32_t abyte[4], bbyte[4];
    #pragma unroll
    for (int mt = 0; mt < 4; ++mt) {
        int row = mt * 16 + lr;
        abyte[mt] = (uint32_t)(row * 64 + lg * 16) ^ (uint32_t)((lr & 7) << 4);
    }
    #pragma unroll
    for (int nt = 0; nt < 4; ++nt) {
        int nn = wn + nt * 16 + lr;
        bbyte[nt] = (uint32_t)(nn * 64 + lg * 16) ^ (uint32_t)((lr & 7) << 4);
    }

    const int S1 = K1 / 32;
    #pragma unroll 1
    for (int s = 0; s < 2 * S1; ++s) {
        const float* __restrict__ A = (s < S1) ? A1 : A2;
        const int k0 = ((s < S1) ? s : s - S1) * 32;

        #pragma unroll
        for (int p = 0; p < 2; ++p) {
            int idx = tid + p * 256;
            int r = idx >> 3;
            int k = (idx & 7) * 4;
            int gr = row0 + r;
            float4 v = make_float4(0.f, 0.f, 0.f, 0.f);
            if (gr < n) v = *(const float4*)(A + (size_t)gr * K1 + k0 + k);
            bf16x4 h4, l4;
            float vv[4] = {v.x, v.y, v.z, v.w};
            #pragma unroll
            for (int j = 0; j < 4; ++j) {
                __bf16 h = (__bf16)vv[j];
                h4[j] = h;
                l4[j] = (__bf16)(vv[j] - (float)h);
            }
            uint32_t byte = (uint32_t)(r * 64 + k * 2) ^ (uint32_t)((r & 7) << 4);
            *(bf16x4*)(lds_ahi + byte) = h4;
            *(bf16x4*)(lds_alo + byte) = l4;
        }
        {
            const uint8_t* __restrict__ Wstep = Wpre + (size_t)s * 32768;
            #pragma unroll
            for (int c = 0; c < 8; ++c) {
                int chunk = tid + c * 256;
                *(uint4*)(lds_w + chunk * 16) = *(const uint4*)(Wstep + chunk * 16);
            }
        }
        __syncthreads();

        bf16x8 ahi[4], alo[4], bhi[4], blo[4];
        #pragma unroll
        for (int mt = 0; mt < 4; ++mt) {
            ahi[mt] = *(const bf16x8*)(lds_ahi + abyte[mt]);
            alo[mt] = *(const bf16x8*)(lds_alo + abyte[mt]);
        }
        #pragma unroll
        for (int nt = 0; nt < 4; ++nt) {
            bhi[nt] = *(const bf16x8*)(lds_w + bbyte[nt]);
            blo[nt] = *(const bf16x8*)(lds_w + 16384 + bbyte[nt]);
        }
        #pragma unroll
        for (int mt = 0; mt < 4; ++mt)
            #pragma unroll
            for (int nt = 0; nt < 4; ++nt) {
                acc[mt][nt] = __builtin_amdgcn_mfma_f32_16x16x32_bf16(ahi[mt], bhi[nt], acc[mt][nt], 0, 0, 0);
                acc[mt][nt] = __builtin_amdgcn_mfma_f32_16x16x32_bf16(alo[mt], bhi[nt], acc[mt][nt], 0, 0, 0);
                acc[mt][nt] = __builtin_amdgcn_mfma_f32_16x16x32_bf16(ahi[mt], blo[nt], acc[mt][nt], 0, 0, 0);
            }
        __syncthreads();
    }

    #pragma unroll
    for (int nt = 0; nt < 4; ++nt) {
        int col = wn + nt * 16 + lr;
        float bv = bias[col];
        #pragma unroll
        for (int mt = 0; mt < 4; ++mt) {
            #pragma unroll
            for (int rr = 0; rr < 4; ++rr) {
                int grow = row0 + mt * 16 + lg * 4 + rr;
                if (grow < n)
                    out[(size_t)grow * 256 + col] = fmaxf(acc[mt][nt][rr] + bv, 0.f);
            }
        }
    }
}

extern "C" void kernel_launch(void* const* d_in, const int* in_sizes, int n_in,
                              void* d_out, int out_size, void* d_ws, size_t ws_size,
                              hipStream_t stream) {
    const float* x   = (const float*)d_in[0];
    const int* edge  = (const int*)d_in[1];
    const float* Wl0 = (const float*)d_in[2];
    const float* bl0 = (const float*)d_in[3];
    const float* Wr0 = (const float*)d_in[4];
    const float* Wl1 = (const float*)d_in[5];
    const float* bl1 = (const float*)d_in[6];
    const float* Wr1 = (const float*)d_in[7];
    const float* Wl2 = (const float*)d_in[8];
    const float* bl2 = (const float*)d_in[9];
    const float* Wr2 = (const float*)d_in[10];

    int n = in_sizes[0] / 128;   // 50000
    int E = in_sizes[1] / 2;     // 800000
    const int* src = edge;
    const int* dst = edge + E;

    char* wptr = (char*)d_ws;
    auto alloc = [&](size_t bytes) { char* p = wptr; wptr += align_up(bytes, 256); return p; };
    int*     deg    = (int*)alloc((size_t)n * 4);
    int*     rowptr = (int*)alloc(((size_t)n + 1) * 4);
    int*     cursor = (int*)alloc((size_t)n * 4);
    int*     csr    = (int*)alloc((size_t)E * 4);
    float*   invd   = (float*)alloc((size_t)n * 4);
    int*     bsums  = (int*)alloc(256 * 4);
    int*     boff   = (int*)alloc(256 * 4);
    uint8_t* Wp0    = (uint8_t*)alloc(8 * 32768);
    uint8_t* Wp1    = (uint8_t*)alloc(16 * 32768);
    uint8_t* Wp2    = (uint8_t*)alloc(16 * 32768);
    float*   aggs   = (float*)alloc((size_t)n * 256 * 4);
    float*   h1     = (float*)alloc((size_t)n * 256 * 4);
    float*   h0     = (float*)d_out;

    int NB = (n + 1023) / 1024;  // 49
    hipMemsetAsync(deg, 0, (size_t)n * 4, stream);
    deg_kernel<<<(E + 255) / 256, 256, 0, stream>>>(dst, deg, E);
    scan_a<<<NB, 256, 0, stream>>>(deg, bsums, n);
    scan_b<<<1, 256, 0, stream>>>(bsums, boff, NB, rowptr + n);
    scan_c<<<NB, 256, 0, stream>>>(deg, boff, rowptr, cursor, invd, n);
    fill_kernel<<<(E + 255) / 256, 256, 0, stream>>>(src, dst, cursor, csr, E);

    convert_w<<<2 * 128 / 4, 256, 0, stream>>>(Wl0, Wr0, Wp0, 128);
    convert_w<<<2 * 256 / 4, 256, 0, stream>>>(Wl1, Wr1, Wp1, 256);
    convert_w<<<2 * 256 / 4, 256, 0, stream>>>(Wl2, Wr2, Wp2, 256);

    int gemm_grid = (n + 63) / 64;
    // layer 0: C=128 -> 256 (8 nodes/block in agg)
    agg_kernel_n<128><<<(n + 7) / 8, 256, 0, stream>>>(x, rowptr, csr, invd, aggs, n);
    gemm_mfma<128><<<gemm_grid, 256, 0, stream>>>(aggs, x, Wp0, bl0, h0, n);
    // layer 1: 256 -> 256 (4 nodes/block)
    agg_kernel_n<256><<<(n + 3) / 4, 256, 0, stream>>>(h0, rowptr, csr, invd, aggs, n);
    gemm_mfma<256><<<gemm_grid, 256, 0, stream>>>(aggs, h0, Wp1, bl1, h1, n);
    // layer 2: 256 -> 256
    agg_kernel_n<256><<<(n + 3) / 4, 256, 0, stream>>>(h1, rowptr, csr, invd, aggs, n);
    gemm_mfma<256><<<gemm_grid, 256, 0, stream>>>(aggs, h1, Wp2, bl2, (float*)d_out, n);
}

// Round 5
// 467.964 us; speedup vs baseline: 4.5936x; 1.2809x over previous
//
#include <hip/hip_runtime.h>
#include <cstdint>
#include <cstddef>

// GraphSAGE 3-layer, mean aggregation.
// R4: agg gather was BW-bound (116us @ ~6.9TB/s logical, occupancy 72%, VALU 13%).
// Gather now reads a bf16 copy of the layer input (half the bytes): x converted
// once; h0/h1 bf16 copies written in the GEMM epilogue. Accumulation stays fp32.
// Scan (R3, 3-phase) and split-bf16 MFMA GEMM (R2) unchanged.

typedef __bf16 bf16x8 __attribute__((ext_vector_type(8)));
typedef __bf16 bf16x4 __attribute__((ext_vector_type(4)));
typedef float  f32x4  __attribute__((ext_vector_type(4)));

static inline size_t align_up(size_t x, size_t a) { return (x + a - 1) / a * a; }

__global__ void deg_kernel(const int* __restrict__ dst, int* __restrict__ deg, int E) {
    int i = blockIdx.x * blockDim.x + threadIdx.x;
    if (i < E) atomicAdd(&deg[dst[i]], 1);
}

// ---- 3-phase scan: deg -> rowptr (exclusive), cursor, inv_deg ----
__global__ void scan_a(const int* __restrict__ deg, int* __restrict__ blocksums, int n) {
    __shared__ int ts[256];
    int t = threadIdx.x;
    int base = blockIdx.x * 1024 + t * 4;
    int s = 0;
    #pragma unroll
    for (int j = 0; j < 4; ++j) if (base + j < n) s += deg[base + j];
    ts[t] = s;
    __syncthreads();
    #pragma unroll
    for (int off = 128; off >= 1; off >>= 1) {
        if (t < off) ts[t] += ts[t + off];
        __syncthreads();
    }
    if (t == 0) blocksums[blockIdx.x] = ts[0];
}

__global__ void scan_b(const int* __restrict__ blocksums, int* __restrict__ blockoff,
                       int NB, int* __restrict__ rowptr_n) {
    __shared__ int ts[256];
    int t = threadIdx.x;
    int v = (t < NB) ? blocksums[t] : 0;
    ts[t] = v;
    __syncthreads();
    for (int off = 1; off < 256; off <<= 1) {
        int u = (t >= off) ? ts[t - off] : 0;
        __syncthreads();
        ts[t] += u;
        __syncthreads();
    }
    if (t < NB) blockoff[t] = ts[t] - v;
    if (t == 255) *rowptr_n = ts[255];
}

__global__ void scan_c(const int* __restrict__ deg, const int* __restrict__ blockoff,
                       int* __restrict__ rowptr, int* __restrict__ cursor,
                       float* __restrict__ inv_deg, int n) {
    __shared__ int ts[256];
    int t = threadIdx.x;
    int base = blockIdx.x * 1024 + t * 4;
    int d[4];
    int s = 0;
    #pragma unroll
    for (int j = 0; j < 4; ++j) {
        d[j] = (base + j < n) ? deg[base + j] : 0;
        s += d[j];
    }
    ts[t] = s;
    __syncthreads();
    for (int off = 1; off < 256; off <<= 1) {
        int u = (t >= off) ? ts[t - off] : 0;
        __syncthreads();
        ts[t] += u;
        __syncthreads();
    }
    int ex = ts[t] - s + blockoff[blockIdx.x];
    #pragma unroll
    for (int j = 0; j < 4; ++j) {
        if (base + j < n) {
            rowptr[base + j] = ex;
            cursor[base + j] = ex;
            inv_deg[base + j] = d[j] > 0 ? 1.0f / (float)d[j] : 0.0f;
            ex += d[j];
        }
    }
}

__global__ void fill_kernel(const int* __restrict__ src, const int* __restrict__ dst,
                            int* __restrict__ cursor, int* __restrict__ csr, int E) {
    int i = blockIdx.x * blockDim.x + threadIdx.x;
    if (i < E) {
        int p = atomicAdd(&cursor[dst[i]], 1);
        csr[p] = src[i];
    }
}

// fp32 -> bf16 (RTNE) convert, 8 elems/thread.
__global__ void f32_to_bf16(const float* __restrict__ in, uint16_t* __restrict__ out, int count) {
    int i = (blockIdx.x * blockDim.x + threadIdx.x) * 8;
    if (i >= count) return;
    float4 v0 = *(const float4*)(in + i);
    float4 v1 = *(const float4*)(in + i + 4);
    bf16x8 o;
    o[0] = (__bf16)v0.x; o[1] = (__bf16)v0.y; o[2] = (__bf16)v0.z; o[3] = (__bf16)v0.w;
    o[4] = (__bf16)v1.x; o[5] = (__bf16)v1.y; o[6] = (__bf16)v1.z; o[7] = (__bf16)v1.w;
    *(bf16x8*)(out + i) = o;
}

__device__ inline void addq(float* a, uint32_t u0, uint32_t u1, uint32_t u2, uint32_t u3) {
    uint32_t u[4] = {u0, u1, u2, u3};
    #pragma unroll
    for (int i = 0; i < 4; ++i) {
        a[2 * i]     += __uint_as_float(u[i] << 16);
        a[2 * i + 1] += __uint_as_float(u[i] & 0xffff0000u);
    }
}

// bf16 gather aggregation: C/8 lanes per node, 16B (8 bf16) per lane.
template<int C>
__global__ void agg_bf16(const uint16_t* __restrict__ hb, const int* __restrict__ rowptr,
                         const int* __restrict__ csr, const float* __restrict__ inv_deg,
                         float* __restrict__ aggs, int n) {
    constexpr int LPN = C / 8;
    constexpr int NPB = 256 / LPN;
    int node = blockIdx.x * NPB + (int)(threadIdx.x / LPN);
    if (node >= n) return;
    int sub = threadIdx.x % LPN;
    int b = rowptr[node], e = rowptr[node + 1];
    float acc[8] = {0.f, 0.f, 0.f, 0.f, 0.f, 0.f, 0.f, 0.f};
    const uint4* h4 = (const uint4*)hb;
    int k = b;
    for (; k + 3 < e; k += 4) {
        int s0 = csr[k], s1 = csr[k + 1], s2 = csr[k + 2], s3 = csr[k + 3];
        uint4 q0 = h4[(size_t)s0 * LPN + sub];
        uint4 q1 = h4[(size_t)s1 * LPN + sub];
        uint4 q2 = h4[(size_t)s2 * LPN + sub];
        uint4 q3 = h4[(size_t)s3 * LPN + sub];
        addq(acc, q0.x, q0.y, q0.z, q0.w);
        addq(acc, q1.x, q1.y, q1.z, q1.w);
        addq(acc, q2.x, q2.y, q2.z, q2.w);
        addq(acc, q3.x, q3.y, q3.z, q3.w);
    }
    for (; k < e; ++k) {
        uint4 q = h4[(size_t)csr[k] * LPN + sub];
        addq(acc, q.x, q.y, q.z, q.w);
    }
    float id = inv_deg[node];
    float4 r0 = make_float4(acc[0] * id, acc[1] * id, acc[2] * id, acc[3] * id);
    float4 r1 = make_float4(acc[4] * id, acc[5] * id, acc[6] * id, acc[7] * id);
    *(float4*)(aggs + (size_t)node * C + sub * 8) = r0;
    *(float4*)(aggs + (size_t)node * C + sub * 8 + 4) = r1;
}

// Exact fp32 gather (fallback if ws too small for bf16 copies).
template<int C>
__global__ void agg_kernel_n(const float* __restrict__ h, const int* __restrict__ rowptr,
                             const int* __restrict__ csr, const float* __restrict__ inv_deg,
                             float* __restrict__ aggs, int n) {
    constexpr int LPN = C / 4;
    constexpr int NPB = 256 / LPN;
    int node = blockIdx.x * NPB + (int)(threadIdx.x / LPN);
    if (node >= n) return;
    int sub = threadIdx.x % LPN;
    int b = rowptr[node], e = rowptr[node + 1];
    f32x4 a0 = (f32x4)(0.f), a1 = (f32x4)(0.f), a2 = (f32x4)(0.f), a3 = (f32x4)(0.f);
    const float4* h4 = (const float4*)h;
    int k = b;
    for (; k + 3 < e; k += 4) {
        int s0 = csr[k], s1 = csr[k + 1], s2 = csr[k + 2], s3 = csr[k + 3];
        float4 v0 = h4[(size_t)s0 * LPN + sub];
        float4 v1 = h4[(size_t)s1 * LPN + sub];
        float4 v2 = h4[(size_t)s2 * LPN + sub];
        float4 v3 = h4[(size_t)s3 * LPN + sub];
        a0 += (f32x4){v0.x, v0.y, v0.z, v0.w};
        a1 += (f32x4){v1.x, v1.y, v1.z, v1.w};
        a2 += (f32x4){v2.x, v2.y, v2.z, v2.w};
        a3 += (f32x4){v3.x, v3.y, v3.z, v3.w};
    }
    for (; k < e; ++k) {
        float4 v0 = h4[(size_t)csr[k] * LPN + sub];
        a0 += (f32x4){v0.x, v0.y, v0.z, v0.w};
    }
    f32x4 r = ((a0 + a1) + (a2 + a3)) * inv_deg[node];
    *(float4*)(aggs + (size_t)node * C + sub * 4) = (float4){r[0], r[1], r[2], r[3]};
}

// Pre-convert W = [Wl; Wr] into per-k-step swizzled bf16 hi/lo planes.
__global__ void convert_w(const float* __restrict__ Wl, const float* __restrict__ Wr,
                          uint8_t* __restrict__ Wpre, int K1) {
    int n = threadIdx.x;
    int kbase = blockIdx.x * 4;
    bf16x4 hi4, lo4;
    #pragma unroll
    for (int j = 0; j < 4; ++j) {
        int k = kbase + j;
        float w = (k < K1) ? Wl[(size_t)k * 256 + n] : Wr[(size_t)(k - K1) * 256 + n];
        __bf16 h = (__bf16)w;
        __bf16 l = (__bf16)(w - (float)h);
        hi4[j] = h;
        lo4[j] = l;
    }
    int s = kbase >> 5;
    int kk = kbase & 31;
    uint32_t byte = (uint32_t)((n * 32 + kk) * 2) ^ (uint32_t)((n & 7) << 4);
    *(bf16x4*)(Wpre + (size_t)s * 32768 + byte) = hi4;
    *(bf16x4*)(Wpre + (size_t)s * 32768 + 16384 + byte) = lo4;
}

__device__ inline uint16_t f2bf(float f) {
    __bf16 h = (__bf16)f;
    union { __bf16 b; uint16_t u; } c;
    c.b = h;
    return c.u;
}

// Fused GEMM: out = relu([A1 | A2] @ Wpre + bias). Split-bf16, 3 mfma/frag.
// If outb != null, also writes a bf16 copy of the output (for next layer's gather).
template<int K1>
__global__ __launch_bounds__(256, 2)
void gemm_mfma(const float* __restrict__ A1, const float* __restrict__ A2,
               const uint8_t* __restrict__ Wpre, const float* __restrict__ bias,
               float* __restrict__ out, uint16_t* __restrict__ outb, int n) {
    __shared__ __align__(16) uint8_t lds[4096 * 2 + 32768];
    uint8_t* lds_ahi = lds;
    uint8_t* lds_alo = lds + 4096;
    uint8_t* lds_w   = lds + 8192;

    const int tid = threadIdx.x;
    const int l = tid & 63;
    const int w = tid >> 6;
    const int lr = l & 15;
    const int lg = l >> 4;
    const int row0 = blockIdx.x * 64;
    const int wn = w * 64;

    f32x4 acc[4][4];
    #pragma unroll
    for (int mt = 0; mt < 4; ++mt)
        #pragma unroll
        for (int nt = 0; nt < 4; ++nt)
            acc[mt][nt] = (f32x4)(0.f);

    uint32_t abyte[4], bbyte[4];
    #pragma unroll
    for (int mt = 0; mt < 4; ++mt) {
        int row = mt * 16 + lr;
        abyte[mt] = (uint32_t)(row * 64 + lg * 16) ^ (uint32_t)((lr & 7) << 4);
    }
    #pragma unroll
    for (int nt = 0; nt < 4; ++nt) {
        int nn = wn + nt * 16 + lr;
        bbyte[nt] = (uint32_t)(nn * 64 + lg * 16) ^ (uint32_t)((lr & 7) << 4);
    }

    const int S1 = K1 / 32;
    #pragma unroll 1
    for (int s = 0; s < 2 * S1; ++s) {
        const float* __restrict__ A = (s < S1) ? A1 : A2;
        const int k0 = ((s < S1) ? s : s - S1) * 32;

        #pragma unroll
        for (int p = 0; p < 2; ++p) {
            int idx = tid + p * 256;
            int r = idx >> 3;
            int k = (idx & 7) * 4;
            int gr = row0 + r;
            float4 v = make_float4(0.f, 0.f, 0.f, 0.f);
            if (gr < n) v = *(const float4*)(A + (size_t)gr * K1 + k0 + k);
            bf16x4 h4, l4;
            float vv[4] = {v.x, v.y, v.z, v.w};
            #pragma unroll
            for (int j = 0; j < 4; ++j) {
                __bf16 h = (__bf16)vv[j];
                h4[j] = h;
                l4[j] = (__bf16)(vv[j] - (float)h);
            }
            uint32_t byte = (uint32_t)(r * 64 + k * 2) ^ (uint32_t)((r & 7) << 4);
            *(bf16x4*)(lds_ahi + byte) = h4;
            *(bf16x4*)(lds_alo + byte) = l4;
        }
        {
            const uint8_t* __restrict__ Wstep = Wpre + (size_t)s * 32768;
            #pragma unroll
            for (int c = 0; c < 8; ++c) {
                int chunk = tid + c * 256;
                *(uint4*)(lds_w + chunk * 16) = *(const uint4*)(Wstep + chunk * 16);
            }
        }
        __syncthreads();

        bf16x8 ahi[4], alo[4], bhi[4], blo[4];
        #pragma unroll
        for (int mt = 0; mt < 4; ++mt) {
            ahi[mt] = *(const bf16x8*)(lds_ahi + abyte[mt]);
            alo[mt] = *(const bf16x8*)(lds_alo + abyte[mt]);
        }
        #pragma unroll
        for (int nt = 0; nt < 4; ++nt) {
            bhi[nt] = *(const bf16x8*)(lds_w + bbyte[nt]);
            blo[nt] = *(const bf16x8*)(lds_w + 16384 + bbyte[nt]);
        }
        #pragma unroll
        for (int mt = 0; mt < 4; ++mt)
            #pragma unroll
            for (int nt = 0; nt < 4; ++nt) {
                acc[mt][nt] = __builtin_amdgcn_mfma_f32_16x16x32_bf16(ahi[mt], bhi[nt], acc[mt][nt], 0, 0, 0);
                acc[mt][nt] = __builtin_amdgcn_mfma_f32_16x16x32_bf16(alo[mt], bhi[nt], acc[mt][nt], 0, 0, 0);
                acc[mt][nt] = __builtin_amdgcn_mfma_f32_16x16x32_bf16(ahi[mt], blo[nt], acc[mt][nt], 0, 0, 0);
            }
        __syncthreads();
    }

    #pragma unroll
    for (int nt = 0; nt < 4; ++nt) {
        int col = wn + nt * 16 + lr;
        float bv = bias[col];
        #pragma unroll
        for (int mt = 0; mt < 4; ++mt) {
            #pragma unroll
            for (int rr = 0; rr < 4; ++rr) {
                int grow = row0 + mt * 16 + lg * 4 + rr;
                if (grow < n) {
                    float v = fmaxf(acc[mt][nt][rr] + bv, 0.f);
                    out[(size_t)grow * 256 + col] = v;
                    if (outb) outb[(size_t)grow * 256 + col] = f2bf(v);
                }
            }
        }
    }
}

extern "C" void kernel_launch(void* const* d_in, const int* in_sizes, int n_in,
                              void* d_out, int out_size, void* d_ws, size_t ws_size,
                              hipStream_t stream) {
    const float* x   = (const float*)d_in[0];
    const int* edge  = (const int*)d_in[1];
    const float* Wl0 = (const float*)d_in[2];
    const float* bl0 = (const float*)d_in[3];
    const float* Wr0 = (const float*)d_in[4];
    const float* Wl1 = (const float*)d_in[5];
    const float* bl1 = (const float*)d_in[6];
    const float* Wr1 = (const float*)d_in[7];
    const float* Wl2 = (const float*)d_in[8];
    const float* bl2 = (const float*)d_in[9];
    const float* Wr2 = (const float*)d_in[10];

    int n = in_sizes[0] / 128;   // 50000
    int E = in_sizes[1] / 2;     // 800000
    const int* src = edge;
    const int* dst = edge + E;

    char* wptr = (char*)d_ws;
    auto alloc = [&](size_t bytes) { char* p = wptr; wptr += align_up(bytes, 256); return p; };
    int*     deg    = (int*)alloc((size_t)n * 4);
    int*     rowptr = (int*)alloc(((size_t)n + 1) * 4);
    int*     cursor = (int*)alloc((size_t)n * 4);
    int*     csr    = (int*)alloc((size_t)E * 4);
    float*   invd   = (float*)alloc((size_t)n * 4);
    int*     bsums  = (int*)alloc(256 * 4);
    int*     boff   = (int*)alloc(256 * 4);
    uint8_t* Wp0    = (uint8_t*)alloc(8 * 32768);
    uint8_t* Wp1    = (uint8_t*)alloc(16 * 32768);
    uint8_t* Wp2    = (uint8_t*)alloc(16 * 32768);
    float*   aggs   = (float*)alloc((size_t)n * 256 * 4);
    float*   h1     = (float*)alloc((size_t)n * 256 * 4);
    // bf16 gather copies: xb (n*128) shares space with h1b (n*256) — xb is dead
    // before h1b is written (layer-1 gemm).
    uint16_t* xb_h1b = (uint16_t*)alloc((size_t)n * 256 * 2);
    uint16_t* h0b    = (uint16_t*)alloc((size_t)n * 256 * 2);
    float*   h0     = (float*)d_out;

    bool use_bf16 = ((size_t)(wptr - (char*)d_ws) <= ws_size);
    uint16_t* xb  = xb_h1b;
    uint16_t* h1b = xb_h1b;

    int NB = (n + 1023) / 1024;
    hipMemsetAsync(deg, 0, (size_t)n * 4, stream);
    deg_kernel<<<(E + 255) / 256, 256, 0, stream>>>(dst, deg, E);
    scan_a<<<NB, 256, 0, stream>>>(deg, bsums, n);
    scan_b<<<1, 256, 0, stream>>>(bsums, boff, NB, rowptr + n);
    scan_c<<<NB, 256, 0, stream>>>(deg, boff, rowptr, cursor, invd, n);
    fill_kernel<<<(E + 255) / 256, 256, 0, stream>>>(src, dst, cursor, csr, E);

    convert_w<<<2 * 128 / 4, 256, 0, stream>>>(Wl0, Wr0, Wp0, 128);
    convert_w<<<2 * 256 / 4, 256, 0, stream>>>(Wl1, Wr1, Wp1, 256);
    convert_w<<<2 * 256 / 4, 256, 0, stream>>>(Wl2, Wr2, Wp2, 256);

    int gemm_grid = (n + 63) / 64;
    if (use_bf16) {
        int cx = n * 128;
        f32_to_bf16<<<(cx / 8 + 255) / 256, 256, 0, stream>>>(x, xb, cx);
        // layer 0: C=128 -> 256
        agg_bf16<128><<<(n + 15) / 16, 256, 0, stream>>>(xb, rowptr, csr, invd, aggs, n);
        gemm_mfma<128><<<gemm_grid, 256, 0, stream>>>(aggs, x, Wp0, bl0, h0, h0b, n);
        // layer 1: 256 -> 256
        agg_bf16<256><<<(n + 7) / 8, 256, 0, stream>>>(h0b, rowptr, csr, invd, aggs, n);
        gemm_mfma<256><<<gemm_grid, 256, 0, stream>>>(aggs, h0, Wp1, bl1, h1, h1b, n);
        // layer 2: 256 -> 256
        agg_bf16<256><<<(n + 7) / 8, 256, 0, stream>>>(h1b, rowptr, csr, invd, aggs, n);
        gemm_mfma<256><<<gemm_grid, 256, 0, stream>>>(aggs, h1, Wp2, bl2, (float*)d_out, (uint16_t*)nullptr, n);
    } else {
        agg_kernel_n<128><<<(n + 7) / 8, 256, 0, stream>>>(x, rowptr, csr, invd, aggs, n);
        gemm_mfma<128><<<gemm_grid, 256, 0, stream>>>(aggs, x, Wp0, bl0, h0, (uint16_t*)nullptr, n);
        agg_kernel_n<256><<<(n + 3) / 4, 256, 0, stream>>>(h0, rowptr, csr, invd, aggs, n);
        gemm_mfma<256><<<gemm_grid, 256, 0, stream>>>(aggs, h0, Wp1, bl1, h1, (uint16_t*)nullptr, n);
        agg_kernel_n<256><<<(n + 3) / 4, 256, 0, stream>>>(h1, rowptr, csr, invd, aggs, n);
        gemm_mfma<256><<<gemm_grid, 256, 0, stream>>>(aggs, h1, Wp2, bl2, (float*)d_out, (uint16_t*)nullptr, n);
    }
}

// Round 6
// 419.227 us; speedup vs baseline: 5.1276x; 1.1163x over previous
//
#include <hip/hip_runtime.h>
#include <cstdint>
#include <cstddef>

// GraphSAGE 3-layer, mean aggregation.
// R5: gemm was latency-bound (MfmaUtil 17%, VALU 12%, occupancy 19%, 3.2M LDS
// bank conflicts). W (256-512KB, L2-resident) was re-staged through LDS every
// k-step by every block (400MB of redundant traffic, 40KB LDS -> 2 blocks/CU).
// Now W fragments are read directly global->reg (coalesced 64B lines, L2-hit);
// LDS drops to 8KB (A tile only) -> occupancy VGPR-limited ~4 blocks/CU.
// Scan (R3), bf16 gather agg (R4), split-bf16 MFMA math (R2) unchanged.

typedef __bf16 bf16x8 __attribute__((ext_vector_type(8)));
typedef __bf16 bf16x4 __attribute__((ext_vector_type(4)));
typedef float  f32x4  __attribute__((ext_vector_type(4)));

static inline size_t align_up(size_t x, size_t a) { return (x + a - 1) / a * a; }

__global__ void deg_kernel(const int* __restrict__ dst, int* __restrict__ deg, int E) {
    int i = blockIdx.x * blockDim.x + threadIdx.x;
    if (i < E) atomicAdd(&deg[dst[i]], 1);
}

// ---- 3-phase scan: deg -> rowptr (exclusive), cursor, inv_deg ----
__global__ void scan_a(const int* __restrict__ deg, int* __restrict__ blocksums, int n) {
    __shared__ int ts[256];
    int t = threadIdx.x;
    int base = blockIdx.x * 1024 + t * 4;
    int s = 0;
    #pragma unroll
    for (int j = 0; j < 4; ++j) if (base + j < n) s += deg[base + j];
    ts[t] = s;
    __syncthreads();
    #pragma unroll
    for (int off = 128; off >= 1; off >>= 1) {
        if (t < off) ts[t] += ts[t + off];
        __syncthreads();
    }
    if (t == 0) blocksums[blockIdx.x] = ts[0];
}

__global__ void scan_b(const int* __restrict__ blocksums, int* __restrict__ blockoff,
                       int NB, int* __restrict__ rowptr_n) {
    __shared__ int ts[256];
    int t = threadIdx.x;
    int v = (t < NB) ? blocksums[t] : 0;
    ts[t] = v;
    __syncthreads();
    for (int off = 1; off < 256; off <<= 1) {
        int u = (t >= off) ? ts[t - off] : 0;
        __syncthreads();
        ts[t] += u;
        __syncthreads();
    }
    if (t < NB) blockoff[t] = ts[t] - v;
    if (t == 255) *rowptr_n = ts[255];
}

__global__ void scan_c(const int* __restrict__ deg, const int* __restrict__ blockoff,
                       int* __restrict__ rowptr, int* __restrict__ cursor,
                       float* __restrict__ inv_deg, int n) {
    __shared__ int ts[256];
    int t = threadIdx.x;
    int base = blockIdx.x * 1024 + t * 4;
    int d[4];
    int s = 0;
    #pragma unroll
    for (int j = 0; j < 4; ++j) {
        d[j] = (base + j < n) ? deg[base + j] : 0;
        s += d[j];
    }
    ts[t] = s;
    __syncthreads();
    for (int off = 1; off < 256; off <<= 1) {
        int u = (t >= off) ? ts[t - off] : 0;
        __syncthreads();
        ts[t] += u;
        __syncthreads();
    }
    int ex = ts[t] - s + blockoff[blockIdx.x];
    #pragma unroll
    for (int j = 0; j < 4; ++j) {
        if (base + j < n) {
            rowptr[base + j] = ex;
            cursor[base + j] = ex;
            inv_deg[base + j] = d[j] > 0 ? 1.0f / (float)d[j] : 0.0f;
            ex += d[j];
        }
    }
}

__global__ void fill_kernel(const int* __restrict__ src, const int* __restrict__ dst,
                            int* __restrict__ cursor, int* __restrict__ csr, int E) {
    int i = blockIdx.x * blockDim.x + threadIdx.x;
    if (i < E) {
        int p = atomicAdd(&cursor[dst[i]], 1);
        csr[p] = src[i];
    }
}

// fp32 -> bf16 (RTNE) convert, 8 elems/thread.
__global__ void f32_to_bf16(const float* __restrict__ in, uint16_t* __restrict__ out, int count) {
    int i = (blockIdx.x * blockDim.x + threadIdx.x) * 8;
    if (i >= count) return;
    float4 v0 = *(const float4*)(in + i);
    float4 v1 = *(const float4*)(in + i + 4);
    bf16x8 o;
    o[0] = (__bf16)v0.x; o[1] = (__bf16)v0.y; o[2] = (__bf16)v0.z; o[3] = (__bf16)v0.w;
    o[4] = (__bf16)v1.x; o[5] = (__bf16)v1.y; o[6] = (__bf16)v1.z; o[7] = (__bf16)v1.w;
    *(bf16x8*)(out + i) = o;
}

__device__ inline void addq(float* a, uint32_t u0, uint32_t u1, uint32_t u2, uint32_t u3) {
    uint32_t u[4] = {u0, u1, u2, u3};
    #pragma unroll
    for (int i = 0; i < 4; ++i) {
        a[2 * i]     += __uint_as_float(u[i] << 16);
        a[2 * i + 1] += __uint_as_float(u[i] & 0xffff0000u);
    }
}

// bf16 gather aggregation: C/8 lanes per node, 16B (8 bf16) per lane.
template<int C>
__global__ void agg_bf16(const uint16_t* __restrict__ hb, const int* __restrict__ rowptr,
                         const int* __restrict__ csr, const float* __restrict__ inv_deg,
                         float* __restrict__ aggs, int n) {
    constexpr int LPN = C / 8;
    constexpr int NPB = 256 / LPN;
    int node = blockIdx.x * NPB + (int)(threadIdx.x / LPN);
    if (node >= n) return;
    int sub = threadIdx.x % LPN;
    int b = rowptr[node], e = rowptr[node + 1];
    float acc[8] = {0.f, 0.f, 0.f, 0.f, 0.f, 0.f, 0.f, 0.f};
    const uint4* h4 = (const uint4*)hb;
    int k = b;
    for (; k + 3 < e; k += 4) {
        int s0 = csr[k], s1 = csr[k + 1], s2 = csr[k + 2], s3 = csr[k + 3];
        uint4 q0 = h4[(size_t)s0 * LPN + sub];
        uint4 q1 = h4[(size_t)s1 * LPN + sub];
        uint4 q2 = h4[(size_t)s2 * LPN + sub];
        uint4 q3 = h4[(size_t)s3 * LPN + sub];
        addq(acc, q0.x, q0.y, q0.z, q0.w);
        addq(acc, q1.x, q1.y, q1.z, q1.w);
        addq(acc, q2.x, q2.y, q2.z, q2.w);
        addq(acc, q3.x, q3.y, q3.z, q3.w);
    }
    for (; k < e; ++k) {
        uint4 q = h4[(size_t)csr[k] * LPN + sub];
        addq(acc, q.x, q.y, q.z, q.w);
    }
    float id = inv_deg[node];
    float4 r0 = make_float4(acc[0] * id, acc[1] * id, acc[2] * id, acc[3] * id);
    float4 r1 = make_float4(acc[4] * id, acc[5] * id, acc[6] * id, acc[7] * id);
    *(float4*)(aggs + (size_t)node * C + sub * 8) = r0;
    *(float4*)(aggs + (size_t)node * C + sub * 8 + 4) = r1;
}

// Exact fp32 gather (fallback if ws too small for bf16 copies).
template<int C>
__global__ void agg_kernel_n(const float* __restrict__ h, const int* __restrict__ rowptr,
                             const int* __restrict__ csr, const float* __restrict__ inv_deg,
                             float* __restrict__ aggs, int n) {
    constexpr int LPN = C / 4;
    constexpr int NPB = 256 / LPN;
    int node = blockIdx.x * NPB + (int)(threadIdx.x / LPN);
    if (node >= n) return;
    int sub = threadIdx.x % LPN;
    int b = rowptr[node], e = rowptr[node + 1];
    f32x4 a0 = (f32x4)(0.f), a1 = (f32x4)(0.f), a2 = (f32x4)(0.f), a3 = (f32x4)(0.f);
    const float4* h4 = (const float4*)h;
    int k = b;
    for (; k + 3 < e; k += 4) {
        int s0 = csr[k], s1 = csr[k + 1], s2 = csr[k + 2], s3 = csr[k + 3];
        float4 v0 = h4[(size_t)s0 * LPN + sub];
        float4 v1 = h4[(size_t)s1 * LPN + sub];
        float4 v2 = h4[(size_t)s2 * LPN + sub];
        float4 v3 = h4[(size_t)s3 * LPN + sub];
        a0 += (f32x4){v0.x, v0.y, v0.z, v0.w};
        a1 += (f32x4){v1.x, v1.y, v1.z, v1.w};
        a2 += (f32x4){v2.x, v2.y, v2.z, v2.w};
        a3 += (f32x4){v3.x, v3.y, v3.z, v3.w};
    }
    for (; k < e; ++k) {
        float4 v0 = h4[(size_t)csr[k] * LPN + sub];
        a0 += (f32x4){v0.x, v0.y, v0.z, v0.w};
    }
    f32x4 r = ((a0 + a1) + (a2 + a3)) * inv_deg[node];
    *(float4*)(aggs + (size_t)node * C + sub * 4) = (float4){r[0], r[1], r[2], r[3]};
}

// Pre-convert W = [Wl; Wr] into per-k-step bf16 hi/lo planes.
// Step s (BK=32): [hi 16KB][lo 16KB]; element (k,n) at byte n*64 + (k%32)*2
// (column-major 64B rows -> wave fragment reads cover contiguous 64B lines).
__global__ void convert_w(const float* __restrict__ Wl, const float* __restrict__ Wr,
                          uint8_t* __restrict__ Wpre, int K1) {
    int n = threadIdx.x;
    int kbase = blockIdx.x * 4;
    bf16x4 hi4, lo4;
    #pragma unroll
    for (int j = 0; j < 4; ++j) {
        int k = kbase + j;
        float w = (k < K1) ? Wl[(size_t)k * 256 + n] : Wr[(size_t)(k - K1) * 256 + n];
        __bf16 h = (__bf16)w;
        __bf16 l = (__bf16)(w - (float)h);
        hi4[j] = h;
        lo4[j] = l;
    }
    int s = kbase >> 5;
    int kk = kbase & 31;
    uint32_t byte = (uint32_t)(n * 64 + kk * 2);
    *(bf16x4*)(Wpre + (size_t)s * 32768 + byte) = hi4;
    *(bf16x4*)(Wpre + (size_t)s * 32768 + 16384 + byte) = lo4;
}

__device__ inline uint16_t f2bf(float f) {
    __bf16 h = (__bf16)f;
    union { __bf16 b; uint16_t u; } c;
    c.b = h;
    return c.u;
}

// Fused GEMM: out = relu([A1 | A2] @ Wpre + bias). Split-bf16, 3 mfma/frag.
// A tile staged through 8KB LDS (hi/lo, XOR-swizzled); W fragments read
// directly global->reg (L2-resident, coalesced).
template<int K1>
__global__ __launch_bounds__(256, 3)
void gemm_mfma(const float* __restrict__ A1, const float* __restrict__ A2,
               const uint8_t* __restrict__ Wpre, const float* __restrict__ bias,
               float* __restrict__ out, uint16_t* __restrict__ outb, int n) {
    __shared__ __align__(16) uint8_t lds[8192];
    uint8_t* lds_ahi = lds;          // 64x32 bf16 hi = 4KB
    uint8_t* lds_alo = lds + 4096;   // 4KB

    const int tid = threadIdx.x;
    const int l = tid & 63;
    const int w = tid >> 6;
    const int lr = l & 15;
    const int lg = l >> 4;
    const int row0 = blockIdx.x * 64;
    const int wn = w * 64;

    f32x4 acc[4][4];
    #pragma unroll
    for (int mt = 0; mt < 4; ++mt)
        #pragma unroll
        for (int nt = 0; nt < 4; ++nt)
            acc[mt][nt] = (f32x4)(0.f);

    uint32_t abyte[4], bbyte[4];
    #pragma unroll
    for (int mt = 0; mt < 4; ++mt) {
        int row = mt * 16 + lr;
        abyte[mt] = (uint32_t)(row * 64 + lg * 16) ^ (uint32_t)((lr & 7) << 4);
    }
    #pragma unroll
    for (int nt = 0; nt < 4; ++nt) {
        int nn = wn + nt * 16 + lr;
        bbyte[nt] = (uint32_t)(nn * 64 + lg * 16);   // global offset within plane
    }

    const int S1 = K1 / 32;
    #pragma unroll 1
    for (int s = 0; s < 2 * S1; ++s) {
        const float* __restrict__ A = (s < S1) ? A1 : A2;
        const int k0 = ((s < S1) ? s : s - S1) * 32;
        const uint8_t* __restrict__ Wstep = Wpre + (size_t)s * 32768;

        // preload all 8 W fragments (global->reg, L2-hit); latency hides under
        // A staging + barrier below.
        bf16x8 bhi[4], blo[4];
        #pragma unroll
        for (int nt = 0; nt < 4; ++nt) {
            bhi[nt] = *(const bf16x8*)(Wstep + bbyte[nt]);
            blo[nt] = *(const bf16x8*)(Wstep + 16384 + bbyte[nt]);
        }

        // stage A tile 64x32 fp32 -> split -> LDS hi/lo (swizzled)
        #pragma unroll
        for (int p = 0; p < 2; ++p) {
            int idx = tid + p * 256;
            int r = idx >> 3;
            int k = (idx & 7) * 4;
            int gr = row0 + r;
            float4 v = make_float4(0.f, 0.f, 0.f, 0.f);
            if (gr < n) v = *(const float4*)(A + (size_t)gr * K1 + k0 + k);
            bf16x4 h4, l4;
            float vv[4] = {v.x, v.y, v.z, v.w};
            #pragma unroll
            for (int j = 0; j < 4; ++j) {
                __bf16 h = (__bf16)vv[j];
                h4[j] = h;
                l4[j] = (__bf16)(vv[j] - (float)h);
            }
            uint32_t byte = (uint32_t)(r * 64 + k * 2) ^ (uint32_t)((r & 7) << 4);
            *(bf16x4*)(lds_ahi + byte) = h4;
            *(bf16x4*)(lds_alo + byte) = l4;
        }
        __syncthreads();

        #pragma unroll
        for (int mt = 0; mt < 4; ++mt) {
            bf16x8 ahi = *(const bf16x8*)(lds_ahi + abyte[mt]);
            bf16x8 alo = *(const bf16x8*)(lds_alo + abyte[mt]);
            #pragma unroll
            for (int nt = 0; nt < 4; ++nt) {
                acc[mt][nt] = __builtin_amdgcn_mfma_f32_16x16x32_bf16(ahi, bhi[nt], acc[mt][nt], 0, 0, 0);
                acc[mt][nt] = __builtin_amdgcn_mfma_f32_16x16x32_bf16(alo, bhi[nt], acc[mt][nt], 0, 0, 0);
                acc[mt][nt] = __builtin_amdgcn_mfma_f32_16x16x32_bf16(ahi, blo[nt], acc[mt][nt], 0, 0, 0);
            }
        }
        __syncthreads();
    }

    // epilogue: D row = mt*16 + lg*4 + rr, col = wn + nt*16 + lr
    #pragma unroll
    for (int nt = 0; nt < 4; ++nt) {
        int col = wn + nt * 16 + lr;
        float bv = bias[col];
        #pragma unroll
        for (int mt = 0; mt < 4; ++mt) {
            #pragma unroll
            for (int rr = 0; rr < 4; ++rr) {
                int grow = row0 + mt * 16 + lg * 4 + rr;
                if (grow < n) {
                    float v = fmaxf(acc[mt][nt][rr] + bv, 0.f);
                    out[(size_t)grow * 256 + col] = v;
                    if (outb) outb[(size_t)grow * 256 + col] = f2bf(v);
                }
            }
        }
    }
}

extern "C" void kernel_launch(void* const* d_in, const int* in_sizes, int n_in,
                              void* d_out, int out_size, void* d_ws, size_t ws_size,
                              hipStream_t stream) {
    const float* x   = (const float*)d_in[0];
    const int* edge  = (const int*)d_in[1];
    const float* Wl0 = (const float*)d_in[2];
    const float* bl0 = (const float*)d_in[3];
    const float* Wr0 = (const float*)d_in[4];
    const float* Wl1 = (const float*)d_in[5];
    const float* bl1 = (const float*)d_in[6];
    const float* Wr1 = (const float*)d_in[7];
    const float* Wl2 = (const float*)d_in[8];
    const float* bl2 = (const float*)d_in[9];
    const float* Wr2 = (const float*)d_in[10];

    int n = in_sizes[0] / 128;   // 50000
    int E = in_sizes[1] / 2;     // 800000
    const int* src = edge;
    const int* dst = edge + E;

    char* wptr = (char*)d_ws;
    auto alloc = [&](size_t bytes) { char* p = wptr; wptr += align_up(bytes, 256); return p; };
    int*     deg    = (int*)alloc((size_t)n * 4);
    int*     rowptr = (int*)alloc(((size_t)n + 1) * 4);
    int*     cursor = (int*)alloc((size_t)n * 4);
    int*     csr    = (int*)alloc((size_t)E * 4);
    float*   invd   = (float*)alloc((size_t)n * 4);
    int*     bsums  = (int*)alloc(256 * 4);
    int*     boff   = (int*)alloc(256 * 4);
    uint8_t* Wp0    = (uint8_t*)alloc(8 * 32768);
    uint8_t* Wp1    = (uint8_t*)alloc(16 * 32768);
    uint8_t* Wp2    = (uint8_t*)alloc(16 * 32768);
    float*   aggs   = (float*)alloc((size_t)n * 256 * 4);
    float*   h1     = (float*)alloc((size_t)n * 256 * 4);
    // bf16 gather copies: xb (n*128) shares space with h1b (n*256) — xb is dead
    // before h1b is written (layer-1 gemm).
    uint16_t* xb_h1b = (uint16_t*)alloc((size_t)n * 256 * 2);
    uint16_t* h0b    = (uint16_t*)alloc((size_t)n * 256 * 2);
    float*   h0     = (float*)d_out;

    bool use_bf16 = ((size_t)(wptr - (char*)d_ws) <= ws_size);
    uint16_t* xb  = xb_h1b;
    uint16_t* h1b = xb_h1b;

    int NB = (n + 1023) / 1024;
    hipMemsetAsync(deg, 0, (size_t)n * 4, stream);
    deg_kernel<<<(E + 255) / 256, 256, 0, stream>>>(dst, deg, E);
    scan_a<<<NB, 256, 0, stream>>>(deg, bsums, n);
    scan_b<<<1, 256, 0, stream>>>(bsums, boff, NB, rowptr + n);
    scan_c<<<NB, 256, 0, stream>>>(deg, boff, rowptr, cursor, invd, n);
    fill_kernel<<<(E + 255) / 256, 256, 0, stream>>>(src, dst, cursor, csr, E);

    convert_w<<<2 * 128 / 4, 256, 0, stream>>>(Wl0, Wr0, Wp0, 128);
    convert_w<<<2 * 256 / 4, 256, 0, stream>>>(Wl1, Wr1, Wp1, 256);
    convert_w<<<2 * 256 / 4, 256, 0, stream>>>(Wl2, Wr2, Wp2, 256);

    int gemm_grid = (n + 63) / 64;
    if (use_bf16) {
        int cx = n * 128;
        f32_to_bf16<<<(cx / 8 + 255) / 256, 256, 0, stream>>>(x, xb, cx);
        // layer 0: C=128 -> 256
        agg_bf16<128><<<(n + 15) / 16, 256, 0, stream>>>(xb, rowptr, csr, invd, aggs, n);
        gemm_mfma<128><<<gemm_grid, 256, 0, stream>>>(aggs, x, Wp0, bl0, h0, h0b, n);
        // layer 1: 256 -> 256
        agg_bf16<256><<<(n + 7) / 8, 256, 0, stream>>>(h0b, rowptr, csr, invd, aggs, n);
        gemm_mfma<256><<<gemm_grid, 256, 0, stream>>>(aggs, h0, Wp1, bl1, h1, h1b, n);
        // layer 2: 256 -> 256
        agg_bf16<256><<<(n + 7) / 8, 256, 0, stream>>>(h1b, rowptr, csr, invd, aggs, n);
        gemm_mfma<256><<<gemm_grid, 256, 0, stream>>>(aggs, h1, Wp2, bl2, (float*)d_out, (uint16_t*)nullptr, n);
    } else {
        agg_kernel_n<128><<<(n + 7) / 8, 256, 0, stream>>>(x, rowptr, csr, invd, aggs, n);
        gemm_mfma<128><<<gemm_grid, 256, 0, stream>>>(aggs, x, Wp0, bl0, h0, (uint16_t*)nullptr, n);
        agg_kernel_n<256><<<(n + 3) / 4, 256, 0, stream>>>(h0, rowptr, csr, invd, aggs, n);
        gemm_mfma<256><<<gemm_grid, 256, 0, stream>>>(aggs, h0, Wp1, bl1, h1, (uint16_t*)nullptr, n);
        agg_kernel_n<256><<<(n + 3) / 4, 256, 0, stream>>>(h1, rowptr, csr, invd, aggs, n);
        gemm_mfma<256><<<gemm_grid, 256, 0, stream>>>(aggs, h1, Wp2, bl2, (float*)d_out, (uint16_t*)nullptr, n);
    }
}